// Round 1
// baseline (1135.471 us; speedup 1.0000x reference)
//
#include <hip/hip_runtime.h>

#define B64 64
#define NNODES 102400

__device__ __forceinline__ float ftanh(float x) {
    // tanh via exp, overflow-safe: e = exp(-2|x|) in (0,1]
    float a = fabsf(x);
    float e = __expf(-2.0f * a);
    float t = (1.0f - e) / (1.0f + e);
    return copysignf(t, x);
}

// ---------------- FC layers ----------------
// h1t[o*64+b] = tanh(sum_k x[b,k]*w1[o,k] + b1[o]);  o in [0,1024), k in [0,128)
__global__ __launch_bounds__(256) void fc1_kernel(
    const float* __restrict__ x, const float* __restrict__ w1,
    const float* __restrict__ b1, float* __restrict__ h1t)
{
    const int b = threadIdx.x & 63;
    const int o = blockIdx.x * 4 + (threadIdx.x >> 6);
    const float* xr = x + b * 128;
    const float* wr = w1 + o * 128;
    float acc = 0.f;
#pragma unroll
    for (int k = 0; k < 128; ++k) acc = fmaf(xr[k], wr[k], acc);
    h1t[o * 64 + b] = ftanh(acc + b1[o]);
}

// h2t[o*64+b] = tanh(sum_k h1t[k*64+b]*w2[o,k] + b2[o]); o in [0,12832), k in [0,1024)
__global__ __launch_bounds__(256) void fc2_kernel(
    const float* __restrict__ h1t, const float* __restrict__ w2,
    const float* __restrict__ b2, float* __restrict__ h2t)
{
    const int b = threadIdx.x & 63;
    const int o = blockIdx.x * 4 + (threadIdx.x >> 6);
    const float* wr = w2 + (size_t)o * 1024;
    float acc = 0.f;
    for (int k = 0; k < 1024; k += 8) {
#pragma unroll
        for (int u = 0; u < 8; ++u)
            acc = fmaf(h1t[(k + u) * 64 + b], wr[k + u], acc);
    }
    h2t[o * 64 + b] = ftanh(acc + b2[o]);
}

// ---------------- ConvTranspose1d (stride 4, K=32, pad 16) ----------------
// x logical [CIN][Lin][64] via (ci*cistride + j*jstride + b); w torch layout (CIN, COUT, 32)
// y[co][t][b] = tanh(bias[co] + sum_ci sum_{8 taps} x[ci][j][b] * w[ci][co][k]),  k = t+16-4j
template<int CIN, int COUT>
__global__ __launch_bounds__(256) void convt_kernel(
    const float* __restrict__ x, int cistride, int jstride,
    const float* __restrict__ w, const float* __restrict__ bias,
    float* __restrict__ y, int Lin, int Lout)
{
    const int b = threadIdx.x & 63;
    const int t = blockIdx.x * 4 + (threadIdx.x >> 6);
    if (t >= Lout) return;
    const int tp  = t + 16;
    const int jhi = tp >> 2;
    const int k0  = tp & 3;
    float acc[COUT];
#pragma unroll
    for (int co = 0; co < COUT; ++co) acc[co] = bias[co];
#pragma unroll
    for (int d = 0; d < 8; ++d) {
        const int j = jhi - d;
        if (j < 0 || j >= Lin) continue;     // wave-uniform branch
        const int k = k0 + 4 * d;
        const float* xp = x + (size_t)j * jstride + b;
        const float* wp = w + k;
#pragma unroll
        for (int ci = 0; ci < CIN; ++ci) {
            const float xv = xp[(size_t)ci * cistride];
            const float* wpc = wp + ci * COUT * 32;
#pragma unroll
            for (int co = 0; co < COUT; ++co)
                acc[co] = fmaf(xv, wpc[co * 32], acc[co]);
        }
    }
#pragma unroll
    for (int co = 0; co < COUT; ++co)
        y[((size_t)co * Lout + t) * 64 + b] = ftanh(acc[co]);
}

// ---------------- Final gather + NearestNeighbouring + activations ----------------
// d0/d1: [NNODES][64] (conv4 outputs per sfc). out[b*N+n] = tanh(z0+z1)
__global__ __launch_bounds__(256) void final_kernel(
    const float* __restrict__ d0, const float* __restrict__ d1,
    const float* __restrict__ nn_w, const float* __restrict__ nn_b,
    const int* __restrict__ mi, const int* __restrict__ oi, const int* __restrict__ pi,
    float* __restrict__ out)
{
    const int b = threadIdx.x & 63;
    const int n = blockIdx.x * 4 + (threadIdx.x >> 6);
    float z = 0.f;
    {
        const int m = mi[n], o = oi[n], p = pi[n];
        const float* wv = nn_w + (size_t)n * 3;
        float v = wv[0] * d0[(size_t)m * 64 + b]
                + wv[1] * d0[(size_t)o * 64 + b]
                + wv[2] * d0[(size_t)p * 64 + b] + nn_b[n];
        z += ftanh(v);
    }
    {
        const int m = mi[NNODES + n], o = oi[NNODES + n], p = pi[NNODES + n];
        const float* wv = nn_w + (size_t)(NNODES + n) * 3;
        float v = wv[0] * d1[(size_t)m * 64 + b]
                + wv[1] * d1[(size_t)o * 64 + b]
                + wv[2] * d1[(size_t)p * 64 + b] + nn_b[NNODES + n];
        z += ftanh(v);
    }
    out[(size_t)b * NNODES + n] = ftanh(z);
}

extern "C" void kernel_launch(void* const* d_in, const int* in_sizes, int n_in,
                              void* d_out, int out_size, void* d_ws, size_t ws_size,
                              hipStream_t stream)
{
    const float* x     = (const float*)d_in[0];
    const float* fc_w1 = (const float*)d_in[1];
    const float* fc_b1 = (const float*)d_in[2];
    const float* fc_w2 = (const float*)d_in[3];
    const float* fc_b2 = (const float*)d_in[4];
    const float* nn_w  = (const float*)d_in[5];
    const float* nn_b  = (const float*)d_in[6];
    const int* ord_i   = (const int*)d_in[7];
    const int* minus_i = (const int*)d_in[8];
    const int* plus_i  = (const int*)d_in[9];
    const float* conv_w1 = (const float*)d_in[10];
    const float* conv_b1 = (const float*)d_in[11];
    const float* conv_w2 = (const float*)d_in[12];
    const float* conv_b2 = (const float*)d_in[13];
    const float* conv_w3 = (const float*)d_in[14];
    const float* conv_b3 = (const float*)d_in[15];
    const float* conv_w4 = (const float*)d_in[16];
    const float* conv_b4 = (const float*)d_in[17];
    float* out = (float*)d_out;

    // workspace layout (floats)
    float* ws  = (float*)d_ws;
    float* h1t = ws;                        //  1024*64      = 65,536
    float* h2t = h1t + 65536;               // 12832*64      = 821,248
    float* y1  = h2t + 821248;              // 16*1601*64    = 1,639,424
    float* y2  = y1  + 1639424;             // 16*6401*64    = 6,554,624
    float* y3  = y2  + 6554624;             //  8*25601*64   = 13,107,712
    float* y4  = y3  + 13107712;            // 2 * 102400*64 = 13,107,200
    // total ~141 MB

    fc1_kernel<<<dim3(256),  dim3(256), 0, stream>>>(x, fc_w1, fc_b1, h1t);
    fc2_kernel<<<dim3(3208), dim3(256), 0, stream>>>(h1t, fc_w2, fc_b2, h2t);

    for (int i = 0; i < 2; ++i) {
        float* d_i = y4 + (size_t)i * 6553600;
        // conv1: 16->16, Lin 401 -> Lout 1601; input strided out of h2t (interleaved sfc)
        convt_kernel<16,16><<<dim3(401), dim3(256), 0, stream>>>(
            h2t + i * 64, 401 * 128, 128,
            conv_w1 + i * 16 * 16 * 32, conv_b1 + i * 16, y1, 401, 1601);
        // conv2: 16->16, 1601 -> 6401
        convt_kernel<16,16><<<dim3(1601), dim3(256), 0, stream>>>(
            y1, 1601 * 64, 64,
            conv_w2 + i * 16 * 16 * 32, conv_b2 + i * 16, y2, 1601, 6401);
        // conv3: 16->8, 6401 -> 25601
        convt_kernel<16,8><<<dim3(6401), dim3(256), 0, stream>>>(
            y2, 6401 * 64, 64,
            conv_w3 + i * 16 * 8 * 32, conv_b3 + i * 8, y3, 6401, 25601);
        // conv4: 8->1, 25601 -> 102400; output is already [node][b] (transposed) layout
        convt_kernel<8,1><<<dim3(25600), dim3(256), 0, stream>>>(
            y3, 25601 * 64, 64,
            conv_w4 + i * 8 * 1 * 32, conv_b4 + i * 1, d_i, 25601, 102400);
    }

    final_kernel<<<dim3(25600), dim3(256), 0, stream>>>(
        y4, y4 + 6553600, nn_w, nn_b, minus_i, ord_i, plus_i, out);
}

// Round 2
// 998.682 us; speedup vs baseline: 1.1370x; 1.1370x over previous
//
#include <hip/hip_runtime.h>

#define NNODES 102400

__device__ __forceinline__ float ftanh(float x) {
    float a = fabsf(x);
    float e = __expf(-2.0f * a);
    float t = (1.0f - e) / (1.0f + e);
    return copysignf(t, x);
}

// ---------------- FC layers ----------------
__global__ __launch_bounds__(256) void fc1_kernel(
    const float* __restrict__ x, const float* __restrict__ w1,
    const float* __restrict__ b1, float* __restrict__ h1t)
{
    const int b = threadIdx.x & 63;
    const int o = blockIdx.x * 4 + (threadIdx.x >> 6);
    const float* xr = x + b * 128;
    const float* wr = w1 + o * 128;
    float acc = 0.f;
#pragma unroll
    for (int k = 0; k < 128; ++k) acc = fmaf(xr[k], wr[k], acc);
    h1t[o * 64 + b] = ftanh(acc + b1[o]);
}

// h2t[o*64+b] = tanh(sum_k h1t[k*64+b]*w2[o,k] + b2[o]); wave computes 8 outputs
__global__ __launch_bounds__(256) void fc2_kernel(
    const float* __restrict__ h1t, const float* __restrict__ w2,
    const float* __restrict__ b2, float* __restrict__ h2t)
{
    const int b = threadIdx.x & 63;
    const int wv = threadIdx.x >> 6;
    const int o0 = blockIdx.x * 32 + wv * 8;
    float acc[8] = {0.f, 0.f, 0.f, 0.f, 0.f, 0.f, 0.f, 0.f};
    const float* h1p = h1t + b;
#pragma unroll 2
    for (int k = 0; k < 1024; k += 4) {
        const float h0 = h1p[(k + 0) * 64];
        const float h1 = h1p[(k + 1) * 64];
        const float h2 = h1p[(k + 2) * 64];
        const float h3 = h1p[(k + 3) * 64];
#pragma unroll
        for (int u = 0; u < 8; ++u) {
            const float4 w4 = *reinterpret_cast<const float4*>(w2 + (size_t)(o0 + u) * 1024 + k);
            acc[u] = fmaf(h0, w4.x, acc[u]);
            acc[u] = fmaf(h1, w4.y, acc[u]);
            acc[u] = fmaf(h2, w4.z, acc[u]);
            acc[u] = fmaf(h3, w4.w, acc[u]);
        }
    }
#pragma unroll
    for (int u = 0; u < 8; ++u)
        h2t[(size_t)(o0 + u) * 64 + b] = ftanh(acc[u] + b2[o0 + u]);
}

// ---------------- weight pre-pack: w[i][ci][co][k] -> wp[i][k0][d][ci][co] ----------------
__global__ __launch_bounds__(256) void pack_w_kernel(
    const float* __restrict__ w, float* __restrict__ wp, int CIN, int COUT)
{
    const int idx = blockIdx.x * 256 + threadIdx.x;
    const int total = 2 * CIN * COUT * 32;
    if (idx >= total) return;
    const int k = idx & 31;
    int r = idx >> 5;
    const int co = r % COUT; r /= COUT;
    const int ci = r % CIN;
    const int i  = r / CIN;
    const int k0 = k & 3, d = k >> 2;
    wp[(((i * 4 + k0) * 8 + d) * CIN + ci) * COUT + co] = w[idx];
}

// ---------------- ConvTranspose1d (stride 4, K=32, pad 16), COUT % 4 == 0 ----------------
// x logical [CIN][Lin][64]; packed weights wp[k0][d][CIN][COUT] (per sfc)
template<int CIN, int COUT>
__global__ __launch_bounds__(256) void convt2_kernel(
    const float* __restrict__ x, int cistride, int jstride,
    const float* __restrict__ wp, const float* __restrict__ bias,
    float* __restrict__ y, int Lin, int Lout)
{
    const int b = threadIdx.x & 63;
    const int t = blockIdx.x * 4 + (threadIdx.x >> 6);
    if (t >= Lout) return;
    const int tp  = t + 16;
    const int jhi = tp >> 2;
    const int k0  = tp & 3;
    float acc[COUT];
#pragma unroll
    for (int co = 0; co < COUT; ++co) acc[co] = bias[co];
    const float* xb = x + b;
#pragma unroll
    for (int d = 0; d < 8; ++d) {
        const int j = jhi - d;
        if (j < 0 || j >= Lin) continue;     // wave-uniform
        const float* wrow = wp + (size_t)((k0 * 8 + d) * CIN) * COUT;
        const float* xp = xb + (size_t)j * jstride;
#pragma unroll
        for (int ci = 0; ci < CIN; ++ci) {
            const float xv = xp[(size_t)ci * cistride];
#pragma unroll
            for (int cq = 0; cq < COUT; cq += 4) {
                const float4 w4 = *reinterpret_cast<const float4*>(wrow + ci * COUT + cq);
                acc[cq + 0] = fmaf(xv, w4.x, acc[cq + 0]);
                acc[cq + 1] = fmaf(xv, w4.y, acc[cq + 1]);
                acc[cq + 2] = fmaf(xv, w4.z, acc[cq + 2]);
                acc[cq + 3] = fmaf(xv, w4.w, acc[cq + 3]);
            }
        }
    }
#pragma unroll
    for (int co = 0; co < COUT; ++co)
        y[((size_t)co * Lout + t) * 64 + b] = ftanh(acc[co]);
}

// ---------------- conv4 specialized: CIN=8, COUT=1, 4 t's per wave (same k0) ----------------
// wp packed [k0][d][8]; x [8][Lin][64]
__global__ __launch_bounds__(256) void convt4_kernel(
    const float* __restrict__ x, const float* __restrict__ wp,
    const float* __restrict__ bias, float* __restrict__ y, int Lin)
{
    const int b = threadIdx.x & 63;
    const int widx = threadIdx.x >> 6;
    const int t0 = blockIdx.x * 16 + widx;       // handles t0 + 4*tt, tt=0..3
    const int k0 = (t0 + 16) & 3;
    const int jhi0 = (t0 + 16) >> 2;
    float wreg[8][8];
#pragma unroll
    for (int d = 0; d < 8; ++d)
#pragma unroll
        for (int ci = 0; ci < 8; ++ci)
            wreg[d][ci] = wp[(k0 * 8 + d) * 8 + ci];
    const float bv = bias[0];
    float acc[4] = {bv, bv, bv, bv};
    const float* xb = x + b;
#pragma unroll
    for (int q = 0; q < 11; ++q) {
        const int j = jhi0 - 7 + q;
        if (j < 0 || j >= Lin) continue;         // wave-uniform
        float xv[8];
        const float* xp = xb + (size_t)j * 64;
#pragma unroll
        for (int ci = 0; ci < 8; ++ci)
            xv[ci] = xp[(size_t)ci * (25601 * 64)];
#pragma unroll
        for (int tt = 0; tt < 4; ++tt) {
            const int d = 7 + tt - q;            // compile-time per (q,tt)
            if (d < 0 || d > 7) continue;
#pragma unroll
            for (int ci = 0; ci < 8; ++ci)
                acc[tt] = fmaf(xv[ci], wreg[d][ci], acc[tt]);
        }
    }
#pragma unroll
    for (int tt = 0; tt < 4; ++tt)
        y[(size_t)(t0 + 4 * tt) * 64 + b] = ftanh(acc[tt]);
}

// ---------------- Final gather + NearestNeighbouring ----------------
__global__ __launch_bounds__(256) void final_kernel(
    const float* __restrict__ d0, const float* __restrict__ d1,
    const float* __restrict__ nn_w, const float* __restrict__ nn_b,
    const int* __restrict__ mi, const int* __restrict__ oi, const int* __restrict__ pi,
    float* __restrict__ out)
{
    const int b = threadIdx.x & 63;
    const int n = blockIdx.x * 4 + (threadIdx.x >> 6);
    float z = 0.f;
    {
        const int m = mi[n], o = oi[n], p = pi[n];
        const float* wv = nn_w + (size_t)n * 3;
        float v = wv[0] * d0[(size_t)m * 64 + b]
                + wv[1] * d0[(size_t)o * 64 + b]
                + wv[2] * d0[(size_t)p * 64 + b] + nn_b[n];
        z += ftanh(v);
    }
    {
        const int m = mi[NNODES + n], o = oi[NNODES + n], p = pi[NNODES + n];
        const float* wv = nn_w + (size_t)(NNODES + n) * 3;
        float v = wv[0] * d1[(size_t)m * 64 + b]
                + wv[1] * d1[(size_t)o * 64 + b]
                + wv[2] * d1[(size_t)p * 64 + b] + nn_b[NNODES + n];
        z += ftanh(v);
    }
    out[(size_t)b * NNODES + n] = ftanh(z);
}

extern "C" void kernel_launch(void* const* d_in, const int* in_sizes, int n_in,
                              void* d_out, int out_size, void* d_ws, size_t ws_size,
                              hipStream_t stream)
{
    const float* x     = (const float*)d_in[0];
    const float* fc_w1 = (const float*)d_in[1];
    const float* fc_b1 = (const float*)d_in[2];
    const float* fc_w2 = (const float*)d_in[3];
    const float* fc_b2 = (const float*)d_in[4];
    const float* nn_w  = (const float*)d_in[5];
    const float* nn_b  = (const float*)d_in[6];
    const int* ord_i   = (const int*)d_in[7];
    const int* minus_i = (const int*)d_in[8];
    const int* plus_i  = (const int*)d_in[9];
    const float* conv_w1 = (const float*)d_in[10];
    const float* conv_b1 = (const float*)d_in[11];
    const float* conv_w2 = (const float*)d_in[12];
    const float* conv_b2 = (const float*)d_in[13];
    const float* conv_w3 = (const float*)d_in[14];
    const float* conv_b3 = (const float*)d_in[15];
    const float* conv_w4 = (const float*)d_in[16];
    const float* conv_b4 = (const float*)d_in[17];
    float* out = (float*)d_out;

    // workspace layout (floats)
    float* ws  = (float*)d_ws;
    float* h1t = ws;                        //  1024*64
    float* h2t = h1t + 65536;               // 12832*64
    float* y1  = h2t + 821248;              // 16*1601*64
    float* y2  = y1  + 1639424;             // 16*6401*64
    float* y3  = y2  + 6554624;             //  8*25601*64
    float* y4  = y3  + 13107712;            // 2 * 102400*64
    float* wp1 = y4  + 13107200;            // 2*16*16*32 = 16384
    float* wp2 = wp1 + 16384;               // 16384
    float* wp3 = wp2 + 16384;               // 2*16*8*32 = 8192
    float* wp4 = wp3 + 8192;                // 2*8*1*32  = 512

    fc1_kernel<<<dim3(256),  dim3(256), 0, stream>>>(x, fc_w1, fc_b1, h1t);
    fc2_kernel<<<dim3(401),  dim3(256), 0, stream>>>(h1t, fc_w2, fc_b2, h2t);

    pack_w_kernel<<<dim3(64), dim3(256), 0, stream>>>(conv_w1, wp1, 16, 16);
    pack_w_kernel<<<dim3(64), dim3(256), 0, stream>>>(conv_w2, wp2, 16, 16);
    pack_w_kernel<<<dim3(32), dim3(256), 0, stream>>>(conv_w3, wp3, 16, 8);
    pack_w_kernel<<<dim3(2),  dim3(256), 0, stream>>>(conv_w4, wp4, 8, 1);

    for (int i = 0; i < 2; ++i) {
        float* d_i = y4 + (size_t)i * 6553600;
        // conv1: 16->16, 401 -> 1601; strided input out of h2t (interleaved sfc)
        convt2_kernel<16,16><<<dim3(401), dim3(256), 0, stream>>>(
            h2t + i * 64, 401 * 128, 128,
            wp1 + i * 8192, conv_b1 + i * 16, y1, 401, 1601);
        // conv2: 16->16, 1601 -> 6401
        convt2_kernel<16,16><<<dim3(1601), dim3(256), 0, stream>>>(
            y1, 1601 * 64, 64,
            wp2 + i * 8192, conv_b2 + i * 16, y2, 1601, 6401);
        // conv3: 16->8, 6401 -> 25601
        convt2_kernel<16,8><<<dim3(6401), dim3(256), 0, stream>>>(
            y2, 6401 * 64, 64,
            wp3 + i * 4096, conv_b3 + i * 8, y3, 6401, 25601);
        // conv4: 8->1, 25601 -> 102400 (specialized, 4 t per wave)
        convt4_kernel<<<dim3(6400), dim3(256), 0, stream>>>(
            y3, wp4 + i * 256, conv_b4 + i, d_i, 25601);
    }

    final_kernel<<<dim3(25600), dim3(256), 0, stream>>>(
        y4, y4 + 6553600, nn_w, nn_b, minus_i, ord_i, plus_i, out);
}

// Round 3
// 486.505 us; speedup vs baseline: 2.3339x; 2.0528x over previous
//
#include <hip/hip_runtime.h>

#define NNODES 102400

__device__ __forceinline__ float ftanh(float x) {
    float a = fabsf(x);
    float e = __expf(-2.0f * a);
    float t = (1.0f - e) / (1.0f + e);
    return copysignf(t, x);
}

// ---------------- FC layers ----------------
__global__ __launch_bounds__(256) void fc1_kernel(
    const float* __restrict__ x, const float* __restrict__ w1,
    const float* __restrict__ b1, float* __restrict__ h1t)
{
    const int b = threadIdx.x & 63;
    const int o = blockIdx.x * 4 + __builtin_amdgcn_readfirstlane(threadIdx.x >> 6);
    const float* xr = x + b * 128;
    const float* wr = w1 + o * 128;
    float acc = 0.f;
#pragma unroll
    for (int k = 0; k < 128; ++k) acc = fmaf(xr[k], wr[k], acc);
    h1t[o * 64 + b] = ftanh(acc + b1[o]);
}

// h2t[o*64+b] = tanh(sum_k h1t[k*64+b]*w2[o,k] + b2[o]); wave computes 8 outputs
__global__ __launch_bounds__(256) void fc2_kernel(
    const float* __restrict__ h1t, const float* __restrict__ w2,
    const float* __restrict__ b2, float* __restrict__ h2t)
{
    const int b = threadIdx.x & 63;
    const int wv = __builtin_amdgcn_readfirstlane(threadIdx.x >> 6);
    const int o0 = blockIdx.x * 32 + wv * 8;
    float acc[8] = {0.f, 0.f, 0.f, 0.f, 0.f, 0.f, 0.f, 0.f};
    const float* h1p = h1t + b;
#pragma unroll 2
    for (int k = 0; k < 1024; k += 4) {
        const float h0 = h1p[(k + 0) * 64];
        const float h1 = h1p[(k + 1) * 64];
        const float h2 = h1p[(k + 2) * 64];
        const float h3 = h1p[(k + 3) * 64];
#pragma unroll
        for (int u = 0; u < 8; ++u) {
            const float4 w4 = *reinterpret_cast<const float4*>(w2 + (size_t)(o0 + u) * 1024 + k);
            acc[u] = fmaf(h0, w4.x, acc[u]);
            acc[u] = fmaf(h1, w4.y, acc[u]);
            acc[u] = fmaf(h2, w4.z, acc[u]);
            acc[u] = fmaf(h3, w4.w, acc[u]);
        }
    }
#pragma unroll
    for (int u = 0; u < 8; ++u)
        h2t[(size_t)(o0 + u) * 64 + b] = ftanh(acc[u] + b2[o0 + u]);
}

// ---------------- fused weight pre-pack: w[i][ci][co][k] -> wp[i][k0][d][ci][co] ----------------
__device__ __forceinline__ void pack_one(const float* __restrict__ w, float* __restrict__ wp,
                                         int CIN, int COUT, int idx)
{
    const int k = idx & 31;
    int r = idx >> 5;
    const int co = r % COUT; r /= COUT;
    const int ci = r % CIN;
    const int i  = r / CIN;
    const int k0 = k & 3, d = k >> 2;
    wp[(((i * 4 + k0) * 8 + d) * CIN + ci) * COUT + co] = w[idx];
}

__global__ __launch_bounds__(256) void pack_all_kernel(
    const float* __restrict__ w1, const float* __restrict__ w2,
    const float* __restrict__ w3, const float* __restrict__ w4,
    float* __restrict__ wp1, float* __restrict__ wp2,
    float* __restrict__ wp3, float* __restrict__ wp4)
{
    const int idx = blockIdx.x * 256 + threadIdx.x;
    if (idx < 16384)       pack_one(w1, wp1, 16, 16, idx);
    else if (idx < 32768)  pack_one(w2, wp2, 16, 16, idx - 16384);
    else if (idx < 40960)  pack_one(w3, wp3, 16,  8, idx - 32768);
    else if (idx < 41472)  pack_one(w4, wp4,  8,  1, idx - 40960);
}

// ---------------- ConvTranspose1d (stride 4, K=32, pad 16) ----------------
// Wave handles TT outputs t0, t0+4, .., t0+4(TT-1) sharing weight phase k0.
// The 4 waves of a block cover the 4 residues of the SAME j-window -> L1 sharing.
// x logical [sfc][CIN][Lin][64]; wp [sfc][k0][d][CIN][COUT]
template<int CIN, int COUT, int TT>
__global__ __launch_bounds__(256, 4) void convt3_kernel(
    const float* __restrict__ x, size_t sfc_xstride, int cistride, int jstride,
    const float* __restrict__ wp, int sfc_wstride,
    const float* __restrict__ bias, int sfc_bstride,
    float* __restrict__ y, size_t sfc_ystride,
    int Lin, int Lout)
{
    const int b = threadIdx.x & 63;
    const int widx = __builtin_amdgcn_readfirstlane(threadIdx.x >> 6);
    const int t0 = blockIdx.x * (4 * TT) + widx;
    if (t0 >= Lout) return;
    const int k0   = (t0 + 16) & 3;
    const int jhi0 = (t0 + 16) >> 2;     // jhi for tt; jhi(tt) = jhi0 + tt
    constexpr int NJ = TT + 7;           // x window rows
    const float* xs = x + (size_t)blockIdx.y * sfc_xstride + b;
    const float* wk = wp + blockIdx.y * sfc_wstride + k0 * (8 * CIN * COUT);
    const float* bs = bias + blockIdx.y * sfc_bstride;

    float acc[TT][COUT];
#pragma unroll
    for (int co = 0; co < COUT; ++co) {
        const float bv = bs[co];
#pragma unroll
        for (int tt = 0; tt < TT; ++tt) acc[tt][co] = bv;
    }

    for (int ci = 0; ci < CIN; ++ci) {
        const float* xpc = xs + (size_t)ci * cistride;
        float xv[NJ];
#pragma unroll
        for (int q = 0; q < NJ; ++q) {
            const int j = jhi0 - 7 + q;
            xv[q] = (j >= 0 && j < Lin) ? xpc[(size_t)j * jstride] : 0.f;
        }
        const float* wc = wk + ci * COUT;
#pragma unroll
        for (int d = 0; d < 8; ++d) {
            const float* wd = wc + d * CIN * COUT;
            float wv[COUT];
            if constexpr ((COUT & 3) == 0) {
#pragma unroll
                for (int cq = 0; cq < COUT; cq += 4) {
                    const float4 w4 = *reinterpret_cast<const float4*>(wd + cq);
                    wv[cq + 0] = w4.x; wv[cq + 1] = w4.y;
                    wv[cq + 2] = w4.z; wv[cq + 3] = w4.w;
                }
            } else {
#pragma unroll
                for (int co = 0; co < COUT; ++co) wv[co] = wd[co];
            }
#pragma unroll
            for (int tt = 0; tt < TT; ++tt) {
                const float xx = xv[7 + tt - d];
#pragma unroll
                for (int co = 0; co < COUT; ++co)
                    acc[tt][co] = fmaf(xx, wv[co], acc[tt][co]);
            }
        }
    }
#pragma unroll
    for (int tt = 0; tt < TT; ++tt) {
        const int t = t0 + 4 * tt;
        if (t < Lout) {
#pragma unroll
            for (int co = 0; co < COUT; ++co)
                y[(size_t)blockIdx.y * sfc_ystride + ((size_t)co * Lout + t) * 64 + b] =
                    ftanh(acc[tt][co]);
        }
    }
}

// ---------------- Final gather + NearestNeighbouring (2 nodes per wave) ----------------
__global__ __launch_bounds__(256) void final_kernel(
    const float* __restrict__ d0, const float* __restrict__ d1,
    const float* __restrict__ nn_w, const float* __restrict__ nn_b,
    const int* __restrict__ mi, const int* __restrict__ oi, const int* __restrict__ pi,
    float* __restrict__ out)
{
    const int b = threadIdx.x & 63;
    const int widx = __builtin_amdgcn_readfirstlane(threadIdx.x >> 6);
    const int n0 = blockIdx.x * 8 + widx * 2;
#pragma unroll
    for (int nn = 0; nn < 2; ++nn) {
        const int n = n0 + nn;
        float z = 0.f;
        {
            const int m = mi[n], o = oi[n], p = pi[n];
            const float* wv = nn_w + (size_t)n * 3;
            float v = wv[0] * d0[(size_t)m * 64 + b]
                    + wv[1] * d0[(size_t)o * 64 + b]
                    + wv[2] * d0[(size_t)p * 64 + b] + nn_b[n];
            z += ftanh(v);
        }
        {
            const int m = mi[NNODES + n], o = oi[NNODES + n], p = pi[NNODES + n];
            const float* wv = nn_w + (size_t)(NNODES + n) * 3;
            float v = wv[0] * d1[(size_t)m * 64 + b]
                    + wv[1] * d1[(size_t)o * 64 + b]
                    + wv[2] * d1[(size_t)p * 64 + b] + nn_b[NNODES + n];
            z += ftanh(v);
        }
        out[(size_t)b * NNODES + n] = ftanh(z);
    }
}

extern "C" void kernel_launch(void* const* d_in, const int* in_sizes, int n_in,
                              void* d_out, int out_size, void* d_ws, size_t ws_size,
                              hipStream_t stream)
{
    const float* x     = (const float*)d_in[0];
    const float* fc_w1 = (const float*)d_in[1];
    const float* fc_b1 = (const float*)d_in[2];
    const float* fc_w2 = (const float*)d_in[3];
    const float* fc_b2 = (const float*)d_in[4];
    const float* nn_w  = (const float*)d_in[5];
    const float* nn_b  = (const float*)d_in[6];
    const int* ord_i   = (const int*)d_in[7];
    const int* minus_i = (const int*)d_in[8];
    const int* plus_i  = (const int*)d_in[9];
    const float* conv_w1 = (const float*)d_in[10];
    const float* conv_b1 = (const float*)d_in[11];
    const float* conv_w2 = (const float*)d_in[12];
    const float* conv_b2 = (const float*)d_in[13];
    const float* conv_w3 = (const float*)d_in[14];
    const float* conv_b3 = (const float*)d_in[15];
    const float* conv_w4 = (const float*)d_in[16];
    const float* conv_b4 = (const float*)d_in[17];
    float* out = (float*)d_out;

    // sizes (floats)
    const size_t SZ_Y1 = (size_t)16 * 1601 * 64;   // 1,639,424
    const size_t SZ_Y2 = (size_t)16 * 6401 * 64;   // 6,554,624
    const size_t SZ_Y3 = (size_t)8  * 25601 * 64;  // 13,107,712
    const size_t SZ_Y4 = (size_t)NNODES * 64;      // 6,553,600 per sfc

    // NS = how many SFCs we batch for conv1/conv2 (needs y1,y2 duplicated)
    const size_t need2 = ((size_t)65536 + 821248 + 2 * SZ_Y1 + 2 * SZ_Y2 + SZ_Y3 + 2 * SZ_Y4 + 41984) * 4;
    const int NS = (ws_size >= need2) ? 2 : 1;

    float* ws  = (float*)d_ws;
    float* h1t = ws;                       // 65,536
    float* h2t = h1t + 65536;              // 821,248
    float* y1  = h2t + 821248;             // NS * SZ_Y1
    float* y2  = y1  + (size_t)NS * SZ_Y1; // NS * SZ_Y2
    float* y3  = y2  + (size_t)NS * SZ_Y2; // SZ_Y3 (shared across sfc)
    float* y4  = y3  + SZ_Y3;              // 2 * SZ_Y4
    float* wp1 = y4  + 2 * SZ_Y4;          // 16384
    float* wp2 = wp1 + 16384;              // 16384
    float* wp3 = wp2 + 16384;              // 8192
    float* wp4 = wp3 + 8192;               // 512

    fc1_kernel<<<dim3(256),  dim3(256), 0, stream>>>(x, fc_w1, fc_b1, h1t);
    fc2_kernel<<<dim3(401),  dim3(256), 0, stream>>>(h1t, fc_w2, fc_b2, h2t);
    pack_all_kernel<<<dim3(162), dim3(256), 0, stream>>>(
        conv_w1, conv_w2, conv_w3, conv_w4, wp1, wp2, wp3, wp4);

    // conv1: 16->16, 401 -> 1601 ; conv2: 16->16, 1601 -> 6401 (batched over NS sfc)
    for (int s0 = 0; s0 < 2; s0 += NS) {
        convt3_kernel<16, 16, 2><<<dim3(201, NS), dim3(256), 0, stream>>>(
            h2t + s0 * 64, 64, 401 * 128, 128,
            wp1 + s0 * 8192, 8192, conv_b1 + s0 * 16, 16,
            y1, SZ_Y1, 401, 1601);
        convt3_kernel<16, 16, 2><<<dim3(801, NS), dim3(256), 0, stream>>>(
            y1, SZ_Y1, 1601 * 64, 64,
            wp2 + s0 * 8192, 8192, conv_b2 + s0 * 16, 16,
            y2, SZ_Y2, 1601, 6401);
        if (NS == 1) {
            convt3_kernel<16, 8, 4><<<dim3(1601, 1), dim3(256), 0, stream>>>(
                y2, 0, 6401 * 64, 64,
                wp3 + s0 * 4096, 0, conv_b3 + s0 * 8, 0,
                y3, 0, 6401, 25601);
            convt3_kernel<8, 1, 8><<<dim3(3200, 1), dim3(256), 0, stream>>>(
                y3, 0, 25601 * 64, 64,
                wp4 + s0 * 256, 0, conv_b4 + s0, 0,
                y4 + (size_t)s0 * SZ_Y4, 0, 25601, 102400);
        }
    }
    if (NS == 2) {
        for (int s = 0; s < 2; ++s) {
            convt3_kernel<16, 8, 4><<<dim3(1601, 1), dim3(256), 0, stream>>>(
                y2 + (size_t)s * SZ_Y2, 0, 6401 * 64, 64,
                wp3 + s * 4096, 0, conv_b3 + s * 8, 0,
                y3, 0, 6401, 25601);
            convt3_kernel<8, 1, 8><<<dim3(3200, 1), dim3(256), 0, stream>>>(
                y3, 0, 25601 * 64, 64,
                wp4 + s * 256, 0, conv_b4 + s, 0,
                y4 + (size_t)s * SZ_Y4, 0, 25601, 102400);
        }
    }

    final_kernel<<<dim3(12800), dim3(256), 0, stream>>>(
        y4, y4 + SZ_Y4, nn_w, nn_b, minus_i, ord_i, plus_i, out);
}

// Round 4
// 354.820 us; speedup vs baseline: 3.2001x; 1.3711x over previous
//
#include <hip/hip_runtime.h>

#define NNODES 102400

__device__ __forceinline__ float ftanh(float x) {
    float a = fabsf(x);
    float e = __expf(-2.0f * a);
    float t = (1.0f - e) / (1.0f + e);
    return copysignf(t, x);
}

// ---------------- FC layers ----------------
__global__ __launch_bounds__(256) void fc1_kernel(
    const float* __restrict__ x, const float* __restrict__ w1,
    const float* __restrict__ b1, float* __restrict__ h1t)
{
    const int b = threadIdx.x & 63;
    const int o = blockIdx.x * 4 + __builtin_amdgcn_readfirstlane(threadIdx.x >> 6);
    const float* xr = x + b * 128;
    const float* wr = w1 + o * 128;
    float acc = 0.f;
#pragma unroll
    for (int k = 0; k < 128; ++k) acc = fmaf(xr[k], wr[k], acc);
    h1t[o * 64 + b] = ftanh(acc + b1[o]);
}

// fc2: block = 8 waves; block computes 8 outputs; wave w does K slice [128w,128w+128).
// LDS tree-reduce. Grid = 12832/8 = 1604 blocks.
__global__ __launch_bounds__(512) void fc2_kernel(
    const float* __restrict__ h1t, const float* __restrict__ w2,
    const float* __restrict__ b2, float* __restrict__ h2t)
{
    __shared__ float red[8][8][64];
    const int b = threadIdx.x & 63;
    const int w = __builtin_amdgcn_readfirstlane(threadIdx.x >> 6);   // 0..7
    const int o0 = blockIdx.x * 8;
    const int kbase = w * 128;
    float acc[8] = {0.f, 0.f, 0.f, 0.f, 0.f, 0.f, 0.f, 0.f};
    const float* h1p = h1t + (size_t)kbase * 64 + b;
#pragma unroll 2
    for (int kk = 0; kk < 128; kk += 4) {
        const float h0 = h1p[(kk + 0) * 64];
        const float h1 = h1p[(kk + 1) * 64];
        const float h2 = h1p[(kk + 2) * 64];
        const float h3 = h1p[(kk + 3) * 64];
#pragma unroll
        for (int u = 0; u < 8; ++u) {
            const float4 w4 = *reinterpret_cast<const float4*>(
                w2 + (size_t)(o0 + u) * 1024 + kbase + kk);
            acc[u] = fmaf(h0, w4.x, acc[u]);
            acc[u] = fmaf(h1, w4.y, acc[u]);
            acc[u] = fmaf(h2, w4.z, acc[u]);
            acc[u] = fmaf(h3, w4.w, acc[u]);
        }
    }
#pragma unroll
    for (int u = 0; u < 8; ++u) red[w][u][b] = acc[u];
    __syncthreads();
    // wave w reduces output o=w across the 8 K-slices
    {
        const int o = w;
        float s = red[0][o][b];
#pragma unroll
        for (int j = 1; j < 8; ++j) s += red[j][o][b];
        h2t[(size_t)(o0 + o) * 64 + b] = ftanh(s + b2[o0 + o]);
    }
}

// ---------------- fused weight pre-pack: w[i][ci][co][k] -> wp[i][k0][d][ci][co] ----------------
__device__ __forceinline__ void pack_one(const float* __restrict__ w, float* __restrict__ wp,
                                         int CIN, int COUT, int idx)
{
    const int k = idx & 31;
    int r = idx >> 5;
    const int co = r % COUT; r /= COUT;
    const int ci = r % CIN;
    const int i  = r / CIN;
    const int k0 = k & 3, d = k >> 2;
    wp[(((i * 4 + k0) * 8 + d) * CIN + ci) * COUT + co] = w[idx];
}

__global__ __launch_bounds__(256) void pack_all_kernel(
    const float* __restrict__ w1, const float* __restrict__ w2,
    const float* __restrict__ w3, const float* __restrict__ w4,
    float* __restrict__ wp1, float* __restrict__ wp2,
    float* __restrict__ wp3, float* __restrict__ wp4)
{
    const int idx = blockIdx.x * 256 + threadIdx.x;
    if (idx < 16384)       pack_one(w1, wp1, 16, 16, idx);
    else if (idx < 32768)  pack_one(w2, wp2, 16, 16, idx - 16384);
    else if (idx < 40960)  pack_one(w3, wp3, 16,  8, idx - 32768);
    else if (idx < 41472)  pack_one(w4, wp4,  8,  1, idx - 40960);
}

// ---------------- ConvTranspose1d (stride 4, K=32, pad 16) ----------------
// Wave handles TT outputs t0, t0+4, ..; blockIdx.z selects a group of COUT/COG channels.
// x logical [sfc][CIN][Lin][64]; wp [sfc][k0][d][CIN][COUT]
template<int CIN, int COUT, int TT, int COG>
__global__ __launch_bounds__(256, 4) void convt3_kernel(
    const float* __restrict__ x, size_t sfc_xstride, int cistride, int jstride,
    const float* __restrict__ wp, int sfc_wstride,
    const float* __restrict__ bias, int sfc_bstride,
    float* __restrict__ y, size_t sfc_ystride,
    int Lin, int Lout)
{
    constexpr int CPG = COUT / COG;
    const int b = threadIdx.x & 63;
    const int widx = __builtin_amdgcn_readfirstlane(threadIdx.x >> 6);
    const int t0 = blockIdx.x * (4 * TT) + widx;
    if (t0 >= Lout) return;
    const int cb = blockIdx.z * CPG;
    const int k0   = (t0 + 16) & 3;
    const int jhi0 = (t0 + 16) >> 2;
    constexpr int NJ = TT + 7;
    const float* xs = x + (size_t)blockIdx.y * sfc_xstride + b;
    const float* wk = wp + blockIdx.y * sfc_wstride + k0 * (8 * CIN * COUT) + cb;
    const float* bs = bias + blockIdx.y * sfc_bstride + cb;

    float acc[TT][CPG];
#pragma unroll
    for (int co = 0; co < CPG; ++co) {
        const float bv = bs[co];
#pragma unroll
        for (int tt = 0; tt < TT; ++tt) acc[tt][co] = bv;
    }

    for (int ci = 0; ci < CIN; ++ci) {
        const float* xpc = xs + (size_t)ci * cistride;
        float xv[NJ];
#pragma unroll
        for (int q = 0; q < NJ; ++q) {
            const int j = jhi0 - 7 + q;
            xv[q] = (j >= 0 && j < Lin) ? xpc[(size_t)j * jstride] : 0.f;
        }
        const float* wc = wk + ci * COUT;
#pragma unroll
        for (int d = 0; d < 8; ++d) {
            const float* wd = wc + d * CIN * COUT;
            float wv[CPG];
            if constexpr ((CPG & 3) == 0) {
#pragma unroll
                for (int cq = 0; cq < CPG; cq += 4) {
                    const float4 w4 = *reinterpret_cast<const float4*>(wd + cq);
                    wv[cq + 0] = w4.x; wv[cq + 1] = w4.y;
                    wv[cq + 2] = w4.z; wv[cq + 3] = w4.w;
                }
            } else {
#pragma unroll
                for (int co = 0; co < CPG; ++co) wv[co] = wd[co];
            }
#pragma unroll
            for (int tt = 0; tt < TT; ++tt) {
                const float xx = xv[7 + tt - d];
#pragma unroll
                for (int co = 0; co < CPG; ++co)
                    acc[tt][co] = fmaf(xx, wv[co], acc[tt][co]);
            }
        }
    }
#pragma unroll
    for (int tt = 0; tt < TT; ++tt) {
        const int t = t0 + 4 * tt;
        if (t < Lout) {
#pragma unroll
            for (int co = 0; co < CPG; ++co)
                y[(size_t)blockIdx.y * sfc_ystride + ((size_t)(cb + co) * Lout + t) * 64 + b] =
                    ftanh(acc[tt][co]);
        }
    }
}

// ---------------- Final gather + NearestNeighbouring (2 nodes per wave) ----------------
__global__ __launch_bounds__(256) void final_kernel(
    const float* __restrict__ d0, const float* __restrict__ d1,
    const float* __restrict__ nn_w, const float* __restrict__ nn_b,
    const int* __restrict__ mi, const int* __restrict__ oi, const int* __restrict__ pi,
    float* __restrict__ out)
{
    const int b = threadIdx.x & 63;
    const int widx = __builtin_amdgcn_readfirstlane(threadIdx.x >> 6);
    const int n0 = blockIdx.x * 8 + widx * 2;
#pragma unroll
    for (int nn = 0; nn < 2; ++nn) {
        const int n = n0 + nn;
        float z = 0.f;
        {
            const int m = mi[n], o = oi[n], p = pi[n];
            const float* wv = nn_w + (size_t)n * 3;
            float v = wv[0] * d0[(size_t)m * 64 + b]
                    + wv[1] * d0[(size_t)o * 64 + b]
                    + wv[2] * d0[(size_t)p * 64 + b] + nn_b[n];
            z += ftanh(v);
        }
        {
            const int m = mi[NNODES + n], o = oi[NNODES + n], p = pi[NNODES + n];
            const float* wv = nn_w + (size_t)(NNODES + n) * 3;
            float v = wv[0] * d1[(size_t)m * 64 + b]
                    + wv[1] * d1[(size_t)o * 64 + b]
                    + wv[2] * d1[(size_t)p * 64 + b] + nn_b[NNODES + n];
            z += ftanh(v);
        }
        out[(size_t)b * NNODES + n] = ftanh(z);
    }
}

extern "C" void kernel_launch(void* const* d_in, const int* in_sizes, int n_in,
                              void* d_out, int out_size, void* d_ws, size_t ws_size,
                              hipStream_t stream)
{
    const float* x     = (const float*)d_in[0];
    const float* fc_w1 = (const float*)d_in[1];
    const float* fc_b1 = (const float*)d_in[2];
    const float* fc_w2 = (const float*)d_in[3];
    const float* fc_b2 = (const float*)d_in[4];
    const float* nn_w  = (const float*)d_in[5];
    const float* nn_b  = (const float*)d_in[6];
    const int* ord_i   = (const int*)d_in[7];
    const int* minus_i = (const int*)d_in[8];
    const int* plus_i  = (const int*)d_in[9];
    const float* conv_w1 = (const float*)d_in[10];
    const float* conv_b1 = (const float*)d_in[11];
    const float* conv_w2 = (const float*)d_in[12];
    const float* conv_b2 = (const float*)d_in[13];
    const float* conv_w3 = (const float*)d_in[14];
    const float* conv_b3 = (const float*)d_in[15];
    const float* conv_w4 = (const float*)d_in[16];
    const float* conv_b4 = (const float*)d_in[17];
    float* out = (float*)d_out;

    // sizes (floats)
    const size_t SZ_Y1 = (size_t)16 * 1601 * 64;
    const size_t SZ_Y2 = (size_t)16 * 6401 * 64;
    const size_t SZ_Y3 = (size_t)8  * 25601 * 64;
    const size_t SZ_Y4 = (size_t)NNODES * 64;

    const size_t need2 = ((size_t)65536 + 821248 + 2 * SZ_Y1 + 2 * SZ_Y2 + SZ_Y3 + 2 * SZ_Y4 + 41984) * 4;
    const int NS = (ws_size >= need2) ? 2 : 1;

    float* ws  = (float*)d_ws;
    float* h1t = ws;
    float* h2t = h1t + 65536;
    float* y1  = h2t + 821248;
    float* y2  = y1  + (size_t)NS * SZ_Y1;
    float* y3  = y2  + (size_t)NS * SZ_Y2;
    float* y4  = y3  + SZ_Y3;
    float* wp1 = y4  + 2 * SZ_Y4;
    float* wp2 = wp1 + 16384;
    float* wp3 = wp2 + 16384;
    float* wp4 = wp3 + 8192;

    fc1_kernel<<<dim3(256),  dim3(256), 0, stream>>>(x, fc_w1, fc_b1, h1t);
    fc2_kernel<<<dim3(1604), dim3(512), 0, stream>>>(h1t, fc_w2, fc_b2, h2t);
    pack_all_kernel<<<dim3(162), dim3(256), 0, stream>>>(
        conv_w1, conv_w2, conv_w3, conv_w4, wp1, wp2, wp3, wp4);

    for (int s0 = 0; s0 < 2; s0 += NS) {
        // conv1: 16->16, 401 -> 1601; TT=1, co-split 2 -> grid 401*NS*2
        convt3_kernel<16, 16, 1, 2><<<dim3(401, NS, 2), dim3(256), 0, stream>>>(
            h2t + s0 * 64, 64, 401 * 128, 128,
            wp1 + s0 * 8192, 8192, conv_b1 + s0 * 16, 16,
            y1, SZ_Y1, 401, 1601);
        // conv2: 16->16, 1601 -> 6401; TT=2, co-split 2
        convt3_kernel<16, 16, 2, 2><<<dim3(801, NS, 2), dim3(256), 0, stream>>>(
            y1, SZ_Y1, 1601 * 64, 64,
            wp2 + s0 * 8192, 8192, conv_b2 + s0 * 16, 16,
            y2, SZ_Y2, 1601, 6401);
        if (NS == 1) {
            convt3_kernel<16, 8, 4, 1><<<dim3(1601, 1, 1), dim3(256), 0, stream>>>(
                y2, 0, 6401 * 64, 64,
                wp3 + s0 * 4096, 0, conv_b3 + s0 * 8, 0,
                y3, 0, 6401, 25601);
            convt3_kernel<8, 1, 8, 1><<<dim3(3200, 1, 1), dim3(256), 0, stream>>>(
                y3, 0, 25601 * 64, 64,
                wp4 + s0 * 256, 0, conv_b4 + s0, 0,
                y4 + (size_t)s0 * SZ_Y4, 0, 25601, 102400);
        }
    }
    if (NS == 2) {
        for (int s = 0; s < 2; ++s) {
            convt3_kernel<16, 8, 4, 1><<<dim3(1601, 1, 1), dim3(256), 0, stream>>>(
                y2 + (size_t)s * SZ_Y2, 0, 6401 * 64, 64,
                wp3 + s * 4096, 0, conv_b3 + s * 8, 0,
                y3, 0, 6401, 25601);
            convt3_kernel<8, 1, 8, 1><<<dim3(3200, 1, 1), dim3(256), 0, stream>>>(
                y3, 0, 25601 * 64, 64,
                wp4 + s * 256, 0, conv_b4 + s, 0,
                y4 + (size_t)s * SZ_Y4, 0, 25601, 102400);
        }
    }

    final_kernel<<<dim3(12800), dim3(256), 0, stream>>>(
        y4, y4 + SZ_Y4, nn_w, nn_b, minus_i, ord_i, plus_i, out);
}

// Round 5
// 340.152 us; speedup vs baseline: 3.3381x; 1.0431x over previous
//
#include <hip/hip_runtime.h>

#define NNODES 102400

__device__ __forceinline__ float ftanh(float x) {
    float a = fabsf(x);
    float e = __expf(-2.0f * a);
    float t = (1.0f - e) / (1.0f + e);
    return copysignf(t, x);
}

// ---------------- FC1 ----------------
__global__ __launch_bounds__(256) void fc1_kernel(
    const float* __restrict__ x, const float* __restrict__ w1,
    const float* __restrict__ b1, float* __restrict__ h1t)
{
    const int b = threadIdx.x & 63;
    const int o = blockIdx.x * 4 + __builtin_amdgcn_readfirstlane(threadIdx.x >> 6);
    const float* xr = x + b * 128;
    const float* wr = w1 + o * 128;
    float acc = 0.f;
#pragma unroll
    for (int k = 0; k < 128; ++k) acc = fmaf(xr[k], wr[k], acc);
    h1t[o * 64 + b] = ftanh(acc + b1[o]);
}

// ---------------- FC2 as LDS-tiled GEMM ----------------
// C[o][b] = sum_k W[o][k] * H[k][b];  M=12832, K=1024, N=64.
// Grid (401, 4): o-tile 32, k-split 4 (K=256 each). Block 128 thr (2 waves).
// Thread tile: 4 o x 4 b, k-micro 4. All LDS reads b128, 2-way banks (free).
__global__ __launch_bounds__(128) void fc2_gemm_kernel(
    const float* __restrict__ h1t,   // [1024][64]
    const float* __restrict__ w2,    // [12832][1024]
    float* __restrict__ part)        // [4][12832][64]
{
    __shared__ float Wl[32][68];     // padded: 2-way on compute reads
    __shared__ float Hl[64][64];
    const int t  = threadIdx.x;
    const int o0 = blockIdx.x * 32;
    const int ks = blockIdx.y;
    const int ob = (t >> 4) * 4;     // 0,4,...,28
    const int b4 = (t & 15) * 4;     // 0,4,...,60

    float acc[4][4] = {};
    const int kbase = ks * 256;
#pragma unroll 1
    for (int kt = 0; kt < 4; ++kt) {
        const int k0 = kbase + kt * 64;
        // stage W tile: 32 rows x 64 k (coalesced vector loads)
        {
            const int row = t >> 2;          // 0..31
            const int c0  = (t & 3) * 4;     // 0,4,8,12
            const float* src = w2 + (size_t)(o0 + row) * 1024 + k0;
#pragma unroll
            for (int i = 0; i < 4; ++i) {
                const float4 v = *reinterpret_cast<const float4*>(src + c0 + 16 * i);
                *reinterpret_cast<float4*>(&Wl[row][c0 + 16 * i]) = v;
            }
        }
        // stage H tile: 64 k x 64 b = 16 KB contiguous
        {
            const float* src = h1t + (size_t)k0 * 64;
            float* dst = &Hl[0][0];
#pragma unroll
            for (int i = 0; i < 8; ++i) {
                const int f4 = t + 128 * i;
                const float4 v = *reinterpret_cast<const float4*>(src + f4 * 4);
                *reinterpret_cast<float4*>(dst + f4 * 4) = v;
            }
        }
        __syncthreads();
#pragma unroll
        for (int kk = 0; kk < 16; ++kk) {
            const int k4 = kk * 4;
            float wv[4][4], hv[4][4];
#pragma unroll
            for (int i = 0; i < 4; ++i) {
                const float4 v = *reinterpret_cast<const float4*>(&Wl[ob + i][k4]);
                wv[i][0] = v.x; wv[i][1] = v.y; wv[i][2] = v.z; wv[i][3] = v.w;
            }
#pragma unroll
            for (int j = 0; j < 4; ++j) {
                const float4 v = *reinterpret_cast<const float4*>(&Hl[k4 + j][b4]);
                hv[j][0] = v.x; hv[j][1] = v.y; hv[j][2] = v.z; hv[j][3] = v.w;
            }
#pragma unroll
            for (int i = 0; i < 4; ++i)
#pragma unroll
                for (int j = 0; j < 4; ++j)
#pragma unroll
                    for (int jb = 0; jb < 4; ++jb)
                        acc[i][jb] = fmaf(wv[i][j], hv[j][jb], acc[i][jb]);
        }
        __syncthreads();
    }
    float* pb = part + ((size_t)ks * 12832 + o0) * 64;
#pragma unroll
    for (int i = 0; i < 4; ++i) {
        const float4 v = make_float4(acc[i][0], acc[i][1], acc[i][2], acc[i][3]);
        *reinterpret_cast<float4*>(pb + (size_t)(ob + i) * 64 + b4) = v;
    }
}

__global__ __launch_bounds__(256) void fc2_reduce_kernel(
    const float* __restrict__ part, const float* __restrict__ b2,
    float* __restrict__ h2t)
{
    const int idx = blockIdx.x * 256 + threadIdx.x;   // = o*64+b
    const int o = idx >> 6;
    const float s = part[idx] + part[821248 + idx]
                  + part[1642496 + idx] + part[2463744 + idx];
    h2t[idx] = ftanh(s + b2[o]);
}

// ---------------- fused weight pre-pack: w[i][ci][co][k] -> wp[i][k0][d][ci][co] ----------------
__device__ __forceinline__ void pack_one(const float* __restrict__ w, float* __restrict__ wp,
                                         int CIN, int COUT, int idx)
{
    const int k = idx & 31;
    int r = idx >> 5;
    const int co = r % COUT; r /= COUT;
    const int ci = r % CIN;
    const int i  = r / CIN;
    const int k0 = k & 3, d = k >> 2;
    wp[(((i * 4 + k0) * 8 + d) * CIN + ci) * COUT + co] = w[idx];
}

__global__ __launch_bounds__(256) void pack_all_kernel(
    const float* __restrict__ w1, const float* __restrict__ w2,
    const float* __restrict__ w3, const float* __restrict__ w4,
    float* __restrict__ wp1, float* __restrict__ wp2,
    float* __restrict__ wp3, float* __restrict__ wp4)
{
    const int idx = blockIdx.x * 256 + threadIdx.x;
    if (idx < 16384)       pack_one(w1, wp1, 16, 16, idx);
    else if (idx < 32768)  pack_one(w2, wp2, 16, 16, idx - 16384);
    else if (idx < 40960)  pack_one(w3, wp3, 16,  8, idx - 32768);
    else if (idx < 41472)  pack_one(w4, wp4,  8,  1, idx - 40960);
}

// ---------------- ConvTranspose1d (stride 4, K=32, pad 16) ----------------
// Wave handles TT outputs t0, t0+4, ..; blockIdx.z selects a group of COUT/COG channels.
// x logical [sfc][CIN][Lin][64]; wp [sfc][k0][d][CIN][COUT]
template<int CIN, int COUT, int TT, int COG>
__global__ __launch_bounds__(256, 4) void convt3_kernel(
    const float* __restrict__ x, size_t sfc_xstride, int cistride, int jstride,
    const float* __restrict__ wp, int sfc_wstride,
    const float* __restrict__ bias, int sfc_bstride,
    float* __restrict__ y, size_t sfc_ystride,
    int Lin, int Lout)
{
    constexpr int CPG = COUT / COG;
    const int b = threadIdx.x & 63;
    const int widx = __builtin_amdgcn_readfirstlane(threadIdx.x >> 6);
    const int t0 = blockIdx.x * (4 * TT) + widx;
    if (t0 >= Lout) return;
    const int cb = blockIdx.z * CPG;
    const int k0   = (t0 + 16) & 3;
    const int jhi0 = (t0 + 16) >> 2;
    constexpr int NJ = TT + 7;
    const float* xs = x + (size_t)blockIdx.y * sfc_xstride + b;
    const float* wk = wp + blockIdx.y * sfc_wstride + k0 * (8 * CIN * COUT) + cb;
    const float* bs = bias + blockIdx.y * sfc_bstride + cb;

    float acc[TT][CPG];
#pragma unroll
    for (int co = 0; co < CPG; ++co) {
        const float bv = bs[co];
#pragma unroll
        for (int tt = 0; tt < TT; ++tt) acc[tt][co] = bv;
    }

    for (int ci = 0; ci < CIN; ++ci) {
        const float* xpc = xs + (size_t)ci * cistride;
        float xv[NJ];
#pragma unroll
        for (int q = 0; q < NJ; ++q) {
            const int j = jhi0 - 7 + q;
            xv[q] = (j >= 0 && j < Lin) ? xpc[(size_t)j * jstride] : 0.f;
        }
        const float* wc = wk + ci * COUT;
#pragma unroll
        for (int d = 0; d < 8; ++d) {
            const float* wd = wc + d * CIN * COUT;
            float wv[CPG];
            if constexpr ((CPG & 3) == 0) {
#pragma unroll
                for (int cq = 0; cq < CPG; cq += 4) {
                    const float4 w4 = *reinterpret_cast<const float4*>(wd + cq);
                    wv[cq + 0] = w4.x; wv[cq + 1] = w4.y;
                    wv[cq + 2] = w4.z; wv[cq + 3] = w4.w;
                }
            } else {
#pragma unroll
                for (int co = 0; co < CPG; ++co) wv[co] = wd[co];
            }
#pragma unroll
            for (int tt = 0; tt < TT; ++tt) {
                const float xx = xv[7 + tt - d];
#pragma unroll
                for (int co = 0; co < CPG; ++co)
                    acc[tt][co] = fmaf(xx, wv[co], acc[tt][co]);
            }
        }
    }
#pragma unroll
    for (int tt = 0; tt < TT; ++tt) {
        const int t = t0 + 4 * tt;
        if (t < Lout) {
#pragma unroll
            for (int co = 0; co < CPG; ++co)
                y[(size_t)blockIdx.y * sfc_ystride + ((size_t)(cb + co) * Lout + t) * 64 + b] =
                    ftanh(acc[tt][co]);
        }
    }
}

// ---------------- Final gather + NearestNeighbouring (2 nodes per wave) ----------------
__global__ __launch_bounds__(256) void final_kernel(
    const float* __restrict__ d0, const float* __restrict__ d1,
    const float* __restrict__ nn_w, const float* __restrict__ nn_b,
    const int* __restrict__ mi, const int* __restrict__ oi, const int* __restrict__ pi,
    float* __restrict__ out)
{
    const int b = threadIdx.x & 63;
    const int widx = __builtin_amdgcn_readfirstlane(threadIdx.x >> 6);
    const int n0 = blockIdx.x * 8 + widx * 2;
#pragma unroll
    for (int nn = 0; nn < 2; ++nn) {
        const int n = n0 + nn;
        float z = 0.f;
        {
            const int m = mi[n], o = oi[n], p = pi[n];
            const float* wv = nn_w + (size_t)n * 3;
            float v = wv[0] * d0[(size_t)m * 64 + b]
                    + wv[1] * d0[(size_t)o * 64 + b]
                    + wv[2] * d0[(size_t)p * 64 + b] + nn_b[n];
            z += ftanh(v);
        }
        {
            const int m = mi[NNODES + n], o = oi[NNODES + n], p = pi[NNODES + n];
            const float* wv = nn_w + (size_t)(NNODES + n) * 3;
            float v = wv[0] * d1[(size_t)m * 64 + b]
                    + wv[1] * d1[(size_t)o * 64 + b]
                    + wv[2] * d1[(size_t)p * 64 + b] + nn_b[NNODES + n];
            z += ftanh(v);
        }
        out[(size_t)b * NNODES + n] = ftanh(z);
    }
}

extern "C" void kernel_launch(void* const* d_in, const int* in_sizes, int n_in,
                              void* d_out, int out_size, void* d_ws, size_t ws_size,
                              hipStream_t stream)
{
    const float* x     = (const float*)d_in[0];
    const float* fc_w1 = (const float*)d_in[1];
    const float* fc_b1 = (const float*)d_in[2];
    const float* fc_w2 = (const float*)d_in[3];
    const float* fc_b2 = (const float*)d_in[4];
    const float* nn_w  = (const float*)d_in[5];
    const float* nn_b  = (const float*)d_in[6];
    const int* ord_i   = (const int*)d_in[7];
    const int* minus_i = (const int*)d_in[8];
    const int* plus_i  = (const int*)d_in[9];
    const float* conv_w1 = (const float*)d_in[10];
    const float* conv_b1 = (const float*)d_in[11];
    const float* conv_w2 = (const float*)d_in[12];
    const float* conv_b2 = (const float*)d_in[13];
    const float* conv_w3 = (const float*)d_in[14];
    const float* conv_b3 = (const float*)d_in[15];
    const float* conv_w4 = (const float*)d_in[16];
    const float* conv_b4 = (const float*)d_in[17];
    float* out = (float*)d_out;

    // sizes (floats)
    const size_t SZ_Y1 = (size_t)16 * 1601 * 64;
    const size_t SZ_Y2 = (size_t)16 * 6401 * 64;
    const size_t SZ_Y3 = (size_t)8  * 25601 * 64;
    const size_t SZ_Y4 = (size_t)NNODES * 64;

    const size_t need2 = ((size_t)65536 + 821248 + 2 * SZ_Y1 + 2 * SZ_Y2 + SZ_Y3 + 2 * SZ_Y4 + 41984) * 4;
    const int NS = (ws_size >= need2) ? 2 : 1;

    float* ws  = (float*)d_ws;
    float* h1t = ws;
    float* h2t = h1t + 65536;
    float* y1  = h2t + 821248;
    float* y2  = y1  + (size_t)NS * SZ_Y1;
    float* y3  = y2  + (size_t)NS * SZ_Y2;
    float* y4  = y3  + SZ_Y3;
    float* wp1 = y4  + 2 * SZ_Y4;
    float* wp2 = wp1 + 16384;
    float* wp3 = wp2 + 16384;
    float* wp4 = wp3 + 8192;
    float* part = y3;               // fc2 k-split partials (4*12832*64 floats), reused by conv3 later

    fc1_kernel<<<dim3(256),  dim3(256), 0, stream>>>(x, fc_w1, fc_b1, h1t);
    fc2_gemm_kernel<<<dim3(401, 4), dim3(128), 0, stream>>>(h1t, fc_w2, part);
    fc2_reduce_kernel<<<dim3(3208), dim3(256), 0, stream>>>(part, fc_b2, h2t);
    pack_all_kernel<<<dim3(162), dim3(256), 0, stream>>>(
        conv_w1, conv_w2, conv_w3, conv_w4, wp1, wp2, wp3, wp4);

    for (int s0 = 0; s0 < 2; s0 += NS) {
        // conv1: 16->16, 401 -> 1601; TT=1, co-split 2
        convt3_kernel<16, 16, 1, 2><<<dim3(401, NS, 2), dim3(256), 0, stream>>>(
            h2t + s0 * 64, 64, 401 * 128, 128,
            wp1 + s0 * 8192, 8192, conv_b1 + s0 * 16, 16,
            y1, SZ_Y1, 401, 1601);
        // conv2: 16->16, 1601 -> 6401; TT=4, co-split 2
        convt3_kernel<16, 16, 4, 2><<<dim3(401, NS, 2), dim3(256), 0, stream>>>(
            y1, SZ_Y1, 1601 * 64, 64,
            wp2 + s0 * 8192, 8192, conv_b2 + s0 * 16, 16,
            y2, SZ_Y2, 1601, 6401);
        if (NS == 1) {
            convt3_kernel<16, 8, 6, 1><<<dim3(1067, 1, 1), dim3(256), 0, stream>>>(
                y2, 0, 6401 * 64, 64,
                wp3 + s0 * 4096, 0, conv_b3 + s0 * 8, 0,
                y3, 0, 6401, 25601);
            convt3_kernel<8, 1, 12, 1><<<dim3(2134, 1, 1), dim3(256), 0, stream>>>(
                y3, 0, 25601 * 64, 64,
                wp4 + s0 * 256, 0, conv_b4 + s0, 0,
                y4 + (size_t)s0 * SZ_Y4, 0, 25601, 102400);
        }
    }
    if (NS == 2) {
        for (int s = 0; s < 2; ++s) {
            convt3_kernel<16, 8, 6, 1><<<dim3(1067, 1, 1), dim3(256), 0, stream>>>(
                y2 + (size_t)s * SZ_Y2, 0, 6401 * 64, 64,
                wp3 + s * 4096, 0, conv_b3 + s * 8, 0,
                y3, 0, 6401, 25601);
            convt3_kernel<8, 1, 12, 1><<<dim3(2134, 1, 1), dim3(256), 0, stream>>>(
                y3, 0, 25601 * 64, 64,
                wp4 + s * 256, 0, conv_b4 + s, 0,
                y4 + (size_t)s * SZ_Y4, 0, 25601, 102400);
        }
    }

    final_kernel<<<dim3(12800), dim3(256), 0, stream>>>(
        y4, y4 + SZ_Y4, nn_w, nn_b, minus_i, ord_i, plus_i, out);
}

// Round 6
// 301.098 us; speedup vs baseline: 3.7711x; 1.1297x over previous
//
#include <hip/hip_runtime.h>

#define NNODES 102400

__device__ __forceinline__ float ftanh(float x) {
    float a = fabsf(x);
    float e = __expf(-2.0f * a);
    float t = (1.0f - e) / (1.0f + e);
    return copysignf(t, x);
}

// ---------------- FC1 ----------------
__global__ __launch_bounds__(256) void fc1_kernel(
    const float* __restrict__ x, const float* __restrict__ w1,
    const float* __restrict__ b1, float* __restrict__ h1t)
{
    const int b = threadIdx.x & 63;
    const int o = blockIdx.x * 4 + __builtin_amdgcn_readfirstlane(threadIdx.x >> 6);
    const float* xr = x + b * 128;
    const float* wr = w1 + o * 128;
    float acc = 0.f;
#pragma unroll
    for (int k = 0; k < 128; ++k) acc = fmaf(xr[k], wr[k], acc);
    h1t[o * 64 + b] = ftanh(acc + b1[o]);
}

// ---------------- FC2 as LDS-tiled GEMM ----------------
__global__ __launch_bounds__(128) void fc2_gemm_kernel(
    const float* __restrict__ h1t,   // [1024][64]
    const float* __restrict__ w2,    // [12832][1024]
    float* __restrict__ part)        // [4][12832][64]
{
    __shared__ float Wl[32][68];
    __shared__ float Hl[64][64];
    const int t  = threadIdx.x;
    const int o0 = blockIdx.x * 32;
    const int ks = blockIdx.y;
    const int ob = (t >> 4) * 4;
    const int b4 = (t & 15) * 4;

    float acc[4][4] = {};
    const int kbase = ks * 256;
#pragma unroll 1
    for (int kt = 0; kt < 4; ++kt) {
        const int k0 = kbase + kt * 64;
        {
            const int row = t >> 2;
            const int c0  = (t & 3) * 4;
            const float* src = w2 + (size_t)(o0 + row) * 1024 + k0;
#pragma unroll
            for (int i = 0; i < 4; ++i) {
                const float4 v = *reinterpret_cast<const float4*>(src + c0 + 16 * i);
                *reinterpret_cast<float4*>(&Wl[row][c0 + 16 * i]) = v;
            }
        }
        {
            const float* src = h1t + (size_t)k0 * 64;
            float* dst = &Hl[0][0];
#pragma unroll
            for (int i = 0; i < 8; ++i) {
                const int f4 = t + 128 * i;
                const float4 v = *reinterpret_cast<const float4*>(src + f4 * 4);
                *reinterpret_cast<float4*>(dst + f4 * 4) = v;
            }
        }
        __syncthreads();
#pragma unroll
        for (int kk = 0; kk < 16; ++kk) {
            const int k4 = kk * 4;
            float wv[4][4], hv[4][4];
#pragma unroll
            for (int i = 0; i < 4; ++i) {
                const float4 v = *reinterpret_cast<const float4*>(&Wl[ob + i][k4]);
                wv[i][0] = v.x; wv[i][1] = v.y; wv[i][2] = v.z; wv[i][3] = v.w;
            }
#pragma unroll
            for (int j = 0; j < 4; ++j) {
                const float4 v = *reinterpret_cast<const float4*>(&Hl[k4 + j][b4]);
                hv[j][0] = v.x; hv[j][1] = v.y; hv[j][2] = v.z; hv[j][3] = v.w;
            }
#pragma unroll
            for (int i = 0; i < 4; ++i)
#pragma unroll
                for (int j = 0; j < 4; ++j)
#pragma unroll
                    for (int jb = 0; jb < 4; ++jb)
                        acc[i][jb] = fmaf(wv[i][j], hv[j][jb], acc[i][jb]);
        }
        __syncthreads();
    }
    float* pb = part + ((size_t)ks * 12832 + o0) * 64;
#pragma unroll
    for (int i = 0; i < 4; ++i) {
        const float4 v = make_float4(acc[i][0], acc[i][1], acc[i][2], acc[i][3]);
        *reinterpret_cast<float4*>(pb + (size_t)(ob + i) * 64 + b4) = v;
    }
}

__global__ __launch_bounds__(256) void fc2_reduce_kernel(
    const float* __restrict__ part, const float* __restrict__ b2,
    float* __restrict__ h2t)
{
    const int idx = blockIdx.x * 256 + threadIdx.x;
    const int o = idx >> 6;
    const float s = part[idx] + part[821248 + idx]
                  + part[1642496 + idx] + part[2463744 + idx];
    h2t[idx] = ftanh(s + b2[o]);
}

// ---------------- weight pre-pack: w[i][ci][co][k] -> wp[i][k0][d][ci][co] ----------------
__device__ __forceinline__ void pack_one(const float* __restrict__ w, float* __restrict__ wp,
                                         int CIN, int COUT, int idx)
{
    const int k = idx & 31;
    int r = idx >> 5;
    const int co = r % COUT; r /= COUT;
    const int ci = r % CIN;
    const int i  = r / CIN;
    const int k0 = k & 3, d = k >> 2;
    wp[(((i * 4 + k0) * 8 + d) * CIN + ci) * COUT + co] = w[idx];
}

__global__ __launch_bounds__(256) void pack_all_kernel(
    const float* __restrict__ w1, const float* __restrict__ w2,
    const float* __restrict__ w3, const float* __restrict__ w4,
    float* __restrict__ wp1, float* __restrict__ wp2,
    float* __restrict__ wp3, float* __restrict__ wp4)
{
    const int idx = blockIdx.x * 256 + threadIdx.x;
    if (idx < 16384)       pack_one(w1, wp1, 16, 16, idx);
    else if (idx < 32768)  pack_one(w2, wp2, 16, 16, idx - 16384);
    else if (idx < 40960)  pack_one(w3, wp3, 16,  8, idx - 32768);
    else if (idx < 41472)  pack_one(w4, wp4,  8,  1, idx - 40960);
}

// ---------------- ConvTranspose1d core (stride 4, K=32, pad 16) ----------------
template<int CIN, int CPG, int TT, bool GUARD>
__device__ __forceinline__ void conv_core(
    const float* __restrict__ xs, int cistride, int jstride, int Lin,
    const float* __restrict__ wk, int wco, int jhi0, float (&acc)[TT][CPG])
{
    constexpr int NJ = TT + 7;
    for (int ci = 0; ci < CIN; ++ci) {
        const float* xpc = xs + (size_t)ci * cistride;
        float xv[NJ];
#pragma unroll
        for (int q = 0; q < NJ; ++q) {
            const int j = jhi0 - 7 + q;
            if constexpr (GUARD)
                xv[q] = (j >= 0 && j < Lin) ? xpc[(size_t)j * jstride] : 0.f;
            else
                xv[q] = xpc[(size_t)j * jstride];
        }
        const float* wc = wk + ci * wco;
#pragma unroll
        for (int d = 0; d < 8; ++d) {
            const float* wd = wc + d * CIN * wco;
            float wv[CPG];
            if constexpr ((CPG & 3) == 0) {
#pragma unroll
                for (int cq = 0; cq < CPG; cq += 4) {
                    const float4 w4 = *reinterpret_cast<const float4*>(wd + cq);
                    wv[cq + 0] = w4.x; wv[cq + 1] = w4.y;
                    wv[cq + 2] = w4.z; wv[cq + 3] = w4.w;
                }
            } else {
#pragma unroll
                for (int co = 0; co < CPG; ++co) wv[co] = wd[co];
            }
#pragma unroll
            for (int tt = 0; tt < TT; ++tt) {
                const float xx = xv[7 + tt - d];
#pragma unroll
                for (int co = 0; co < CPG; ++co)
                    acc[tt][co] = fmaf(xx, wv[co], acc[tt][co]);
            }
        }
    }
}

// Wave handles TT outputs t0, t0+4, ..; blockIdx.z = co-group; blockIdx.y = sfc.
template<int CIN, int COUT, int TT, int COG>
__global__ __launch_bounds__(256, 4) void convt3_kernel(
    const float* __restrict__ x, size_t sfc_xstride, int cistride, int jstride,
    const float* __restrict__ wp, int sfc_wstride,
    const float* __restrict__ bias, int sfc_bstride,
    float* __restrict__ y, size_t sfc_ystride,
    int Lin, int Lout)
{
    constexpr int CPG = COUT / COG;
    const int b = threadIdx.x & 63;
    const int widx = __builtin_amdgcn_readfirstlane(threadIdx.x >> 6);
    const int t0 = blockIdx.x * (4 * TT) + widx;
    if (t0 >= Lout) return;
    const int cb = blockIdx.z * CPG;
    const int k0   = (t0 + 16) & 3;
    const int jhi0 = (t0 + 16) >> 2;
    const float* xs = x + (size_t)blockIdx.y * sfc_xstride + b;
    const float* wk = wp + blockIdx.y * sfc_wstride + k0 * (8 * CIN * COUT) + cb;
    const float* bs = bias + blockIdx.y * sfc_bstride + cb;

    float acc[TT][CPG];
#pragma unroll
    for (int co = 0; co < CPG; ++co) {
        const float bv = bs[co];
#pragma unroll
        for (int tt = 0; tt < TT; ++tt) acc[tt][co] = bv;
    }

    const bool interior = (jhi0 >= 7) && (jhi0 + TT - 1 < Lin);
    if (interior)
        conv_core<CIN, CPG, TT, false>(xs, cistride, jstride, Lin, wk, COUT, jhi0, acc);
    else
        conv_core<CIN, CPG, TT, true >(xs, cistride, jstride, Lin, wk, COUT, jhi0, acc);

#pragma unroll
    for (int tt = 0; tt < TT; ++tt) {
        const int t = t0 + 4 * tt;
        if (t < Lout) {
#pragma unroll
            for (int co = 0; co < CPG; ++co)
                y[(size_t)blockIdx.y * sfc_ystride + ((size_t)(cb + co) * Lout + t) * 64 + b] =
                    ftanh(acc[tt][co]);
        }
    }
}

// ---------------- conv4 specialized: COUT=1, weights hoisted to registers ----------------
template<int CIN, int TT, bool GUARD>
__device__ __forceinline__ void conv4_core(
    const float* __restrict__ xs, int cistride, int Lin, int jhi0,
    const float (&wreg)[8][CIN], float (&acc)[TT])
{
    constexpr int NJ = TT + 7;
    for (int ci = 0; ci < CIN; ++ci) {
        const float* xpc = xs + (size_t)ci * cistride;
        float xv[NJ];
#pragma unroll
        for (int q = 0; q < NJ; ++q) {
            const int j = jhi0 - 7 + q;
            if constexpr (GUARD)
                xv[q] = (j >= 0 && j < Lin) ? xpc[(size_t)j * 64] : 0.f;
            else
                xv[q] = xpc[(size_t)j * 64];
        }
#pragma unroll
        for (int d = 0; d < 8; ++d)
#pragma unroll
            for (int tt = 0; tt < TT; ++tt)
                acc[tt] = fmaf(xv[7 + tt - d], wreg[d][ci], acc[tt]);
    }
}

template<int CIN, int TT>
__global__ __launch_bounds__(256, 3) void convt4_kernel(
    const float* __restrict__ x, size_t sfc_xstride, int cistride,
    const float* __restrict__ wp, int sfc_wstride,
    const float* __restrict__ bias, int sfc_bstride,
    float* __restrict__ y, size_t sfc_ystride, int Lin, int Lout)
{
    const int b = threadIdx.x & 63;
    const int widx = __builtin_amdgcn_readfirstlane(threadIdx.x >> 6);
    const int t0 = blockIdx.x * (4 * TT) + widx;
    if (t0 >= Lout) return;
    const int k0   = (t0 + 16) & 3;
    const int jhi0 = (t0 + 16) >> 2;
    const float* wk = wp + blockIdx.y * sfc_wstride + k0 * (8 * CIN);
    float wreg[8][CIN];
#pragma unroll
    for (int d = 0; d < 8; ++d)
#pragma unroll
        for (int ci = 0; ci < CIN; ++ci)
            wreg[d][ci] = wk[d * CIN + ci];
    const float bv = bias[blockIdx.y * sfc_bstride];
    float acc[TT];
#pragma unroll
    for (int tt = 0; tt < TT; ++tt) acc[tt] = bv;
    const float* xs = x + (size_t)blockIdx.y * sfc_xstride + b;

    const bool interior = (jhi0 >= 7) && (jhi0 + TT - 1 < Lin);
    if (interior) conv4_core<CIN, TT, false>(xs, cistride, Lin, jhi0, wreg, acc);
    else          conv4_core<CIN, TT, true >(xs, cistride, Lin, jhi0, wreg, acc);

    float* yb = y + (size_t)blockIdx.y * sfc_ystride;
#pragma unroll
    for (int tt = 0; tt < TT; ++tt) {
        const int t = t0 + 4 * tt;
        if (t < Lout) yb[(size_t)t * 64 + b] = ftanh(acc[tt]);
    }
}

// ---------------- Final gather + NearestNeighbouring ----------------
__global__ __launch_bounds__(256) void final_kernel(
    const float* __restrict__ d0, const float* __restrict__ d1,
    const float* __restrict__ nn_w, const float* __restrict__ nn_b,
    const int* __restrict__ mi, const int* __restrict__ oi, const int* __restrict__ pi,
    float* __restrict__ out)
{
    const int b = threadIdx.x & 63;
    const int widx = __builtin_amdgcn_readfirstlane(threadIdx.x >> 6);
    const int n0 = blockIdx.x * 8 + widx * 2;
#pragma unroll
    for (int nn = 0; nn < 2; ++nn) {
        const int n = n0 + nn;
        float z = 0.f;
        {
            const int m = mi[n], o = oi[n], p = pi[n];
            const float* wv = nn_w + (size_t)n * 3;
            float v = wv[0] * d0[(size_t)m * 64 + b]
                    + wv[1] * d0[(size_t)o * 64 + b]
                    + wv[2] * d0[(size_t)p * 64 + b] + nn_b[n];
            z += ftanh(v);
        }
        {
            const int m = mi[NNODES + n], o = oi[NNODES + n], p = pi[NNODES + n];
            const float* wv = nn_w + (size_t)(NNODES + n) * 3;
            float v = wv[0] * d1[(size_t)m * 64 + b]
                    + wv[1] * d1[(size_t)o * 64 + b]
                    + wv[2] * d1[(size_t)p * 64 + b] + nn_b[NNODES + n];
            z += ftanh(v);
        }
        out[(size_t)b * NNODES + n] = ftanh(z);
    }
}

extern "C" void kernel_launch(void* const* d_in, const int* in_sizes, int n_in,
                              void* d_out, int out_size, void* d_ws, size_t ws_size,
                              hipStream_t stream)
{
    const float* x     = (const float*)d_in[0];
    const float* fc_w1 = (const float*)d_in[1];
    const float* fc_b1 = (const float*)d_in[2];
    const float* fc_w2 = (const float*)d_in[3];
    const float* fc_b2 = (const float*)d_in[4];
    const float* nn_w  = (const float*)d_in[5];
    const float* nn_b  = (const float*)d_in[6];
    const int* ord_i   = (const int*)d_in[7];
    const int* minus_i = (const int*)d_in[8];
    const int* plus_i  = (const int*)d_in[9];
    const float* conv_w1 = (const float*)d_in[10];
    const float* conv_b1 = (const float*)d_in[11];
    const float* conv_w2 = (const float*)d_in[12];
    const float* conv_b2 = (const float*)d_in[13];
    const float* conv_w3 = (const float*)d_in[14];
    const float* conv_b3 = (const float*)d_in[15];
    const float* conv_w4 = (const float*)d_in[16];
    const float* conv_b4 = (const float*)d_in[17];
    float* out = (float*)d_out;

    const size_t SZ_Y1 = (size_t)16 * 1601 * 64;
    const size_t SZ_Y2 = (size_t)16 * 6401 * 64;
    const size_t SZ_Y3 = (size_t)8  * 25601 * 64;
    const size_t SZ_Y4 = (size_t)NNODES * 64;

    // tiering: NY3=2 enables single-dispatch conv3/conv4 over both sfc
    const size_t need22 = 56638976ull * 4;   // NS=2, NY3=2
    const size_t need21 = 43531264ull * 4;   // NS=2, NY3=1
    int NS = 1, NY3 = 1;
    if (ws_size >= need22)      { NS = 2; NY3 = 2; }
    else if (ws_size >= need21) { NS = 2; NY3 = 1; }

    float* ws  = (float*)d_ws;
    float* h1t = ws;
    float* h2t = h1t + 65536;
    float* y1  = h2t + 821248;
    float* y2  = y1  + (size_t)NS * SZ_Y1;
    float* y3  = y2  + (size_t)NS * SZ_Y2;
    float* y4  = y3  + (size_t)NY3 * SZ_Y3;
    float* wp1 = y4  + 2 * SZ_Y4;
    float* wp2 = wp1 + 16384;
    float* wp3 = wp2 + 16384;
    float* wp4 = wp3 + 8192;
    float* part = y3;   // fc2 partials alias y3 (consumed before convs)

    fc1_kernel<<<dim3(256),  dim3(256), 0, stream>>>(x, fc_w1, fc_b1, h1t);
    fc2_gemm_kernel<<<dim3(401, 4), dim3(128), 0, stream>>>(h1t, fc_w2, part);
    fc2_reduce_kernel<<<dim3(3208), dim3(256), 0, stream>>>(part, fc_b2, h2t);
    pack_all_kernel<<<dim3(162), dim3(256), 0, stream>>>(
        conv_w1, conv_w2, conv_w3, conv_w4, wp1, wp2, wp3, wp4);

    for (int s0 = 0; s0 < 2; s0 += NS) {
        // conv1: 16->16, 401 -> 1601; TT=1, co-split 2
        convt3_kernel<16, 16, 1, 2><<<dim3(401, NS, 2), dim3(256), 0, stream>>>(
            h2t + s0 * 64, 64, 401 * 128, 128,
            wp1 + s0 * 8192, 8192, conv_b1 + s0 * 16, 16,
            y1, SZ_Y1, 401, 1601);
        // conv2: 16->16, 1601 -> 6401; TT=4, co-split 2
        convt3_kernel<16, 16, 4, 2><<<dim3(401, NS, 2), dim3(256), 0, stream>>>(
            y1, SZ_Y1, 1601 * 64, 64,
            wp2 + s0 * 8192, 8192, conv_b2 + s0 * 16, 16,
            y2, SZ_Y2, 1601, 6401);
        if (NY3 == 1) {
            for (int s = s0; s < s0 + NS; ++s) {
                const float* xin = y2 + (size_t)(NS == 2 ? (s - s0) : 0) * SZ_Y2;
                convt3_kernel<16, 8, 6, 2><<<dim3(1067, 1, 2), dim3(256), 0, stream>>>(
                    xin, 0, 6401 * 64, 64,
                    wp3 + s * 4096, 0, conv_b3 + s * 8, 0,
                    y3, 0, 6401, 25601);
                convt4_kernel<8, 12><<<dim3(2134, 1), dim3(256), 0, stream>>>(
                    y3, 0, 25601 * 64,
                    wp4 + s * 256, 0, conv_b4 + s, 0,
                    y4 + (size_t)s * SZ_Y4, 0, 25601, 102400);
            }
        }
    }
    if (NY3 == 2) {
        // both sfc in one dispatch each
        convt3_kernel<16, 8, 6, 2><<<dim3(1067, 2, 2), dim3(256), 0, stream>>>(
            y2, SZ_Y2, 6401 * 64, 64,
            wp3, 4096, conv_b3, 8,
            y3, SZ_Y3, 6401, 25601);
        convt4_kernel<8, 12><<<dim3(2134, 2), dim3(256), 0, stream>>>(
            y3, SZ_Y3, 25601 * 64,
            wp4, 256, conv_b4, 1,
            y4, SZ_Y4, 25601, 102400);
    }

    final_kernel<<<dim3(12800), dim3(256), 0, stream>>>(
        y4, y4 + SZ_Y4, nn_w, nn_b, minus_i, ord_i, plus_i, out);
}